// Round 1
// baseline (153.515 us; speedup 1.0000x reference)
//
#include <hip/hip_runtime.h>
#include <stdint.h>

typedef __attribute__((ext_vector_type(4))) float f32x4;
typedef __attribute__((ext_vector_type(8))) short bf16x8;

#define DEV static __device__ __forceinline__

DEV unsigned short f2bf(float f){
  union { float f; uint32_t u; } v; v.f = f;
  return (unsigned short)((v.u + 0x7fffu + ((v.u >> 16) & 1u)) >> 16);
}

DEV f32x4 mfma_bf16(bf16x8 a, bf16x8 b, f32x4 c){
  return __builtin_amdgcn_mfma_f32_16x16x32_bf16(a, b, c, 0, 0, 0);
}

// ---------------- K0a: fm [b][c][l] f32 -> XT [b][l][c] bf16 ----------------
__global__ __launch_bounds__(256) void k_transpose_cvt(const float* __restrict__ fm,
                                                       unsigned short* __restrict__ xt){
  __shared__ float tile[32][33];
  int b = blockIdx.z, c0 = blockIdx.y * 32, l0 = blockIdx.x * 32;
  int tc = threadIdx.x & 31, tr = threadIdx.x >> 5;
  const float* src = fm + ((size_t)b * 512 + c0) * 1024 + l0;
  for (int i = 0; i < 4; i++){
    int r = tr + i * 8;
    tile[r][tc] = src[(size_t)r * 1024 + tc];
  }
  __syncthreads();
  unsigned short* dst = xt + ((size_t)b * 1024 + l0) * 512 + c0;
  for (int i = 0; i < 4; i++){
    int r = tr + i * 8;
    dst[(size_t)r * 512 + tc] = f2bf(tile[tc][r]);
  }
}

// ---------------- K0b: W concat(w_qk,w_v) f32 -> bf16 [1536][512] ----------------
__global__ __launch_bounds__(256) void k_wcvt(const float* __restrict__ wqk,
                                              const float* __restrict__ wv,
                                              unsigned short* __restrict__ wb){
  int idx = blockIdx.x * 256 + threadIdx.x;
  int e = idx * 4;
  if (e >= 1536 * 512) return;
  const float* src = (e < 1024 * 512) ? (wqk + e) : (wv + (e - 1024 * 512));
  f32x4 v = *(const f32x4*)src;
  unsigned short* d = wb + e;
  d[0] = f2bf(v[0]); d[1] = f2bf(v[1]); d[2] = f2bf(v[2]); d[3] = f2bf(v[3]);
}

// ---------------- K1: gemm_bt  C = A(MxK) * B(NxK)^T, bf16, K=512 ----------------
// MODE 0: A = XT_b [1024][512], B = Wqk [1024][512] -> C[l][o] -> q(,scaled)/k [bh][l][d]
// MODE 1: A = Wv [512][512],   B = XT_b [1024][512] -> C[o][l] -> v [bh][dv][l]
template<int MODE>
__global__ __launch_bounds__(256, 3) void k_proj(const unsigned short* __restrict__ Abase,
                                                 const unsigned short* __restrict__ Bbase,
                                                 unsigned short* __restrict__ qbuf,
                                                 unsigned short* __restrict__ kbuf,
                                                 unsigned short* __restrict__ vbuf){
  __shared__ unsigned short Al[128][72];
  __shared__ unsigned short Bl[128][72];
  int b = blockIdx.z;
  const unsigned short* A = Abase + (MODE == 0 ? (size_t)b * 1024 * 512 : 0);
  const unsigned short* B = Bbase + (MODE == 0 ? 0 : (size_t)b * 1024 * 512);
  int m0 = blockIdx.x * 128, n0 = blockIdx.y * 128;
  int t = threadIdx.x;
  int lane = t & 63, w = t >> 6;
  int wm = (w >> 1) * 64, wn = (w & 1) * 64;
  int l15 = lane & 15, lg = lane >> 4;
  f32x4 acc[4][4];
  for (int m = 0; m < 4; m++) for (int n = 0; n < 4; n++) acc[m][n] = (f32x4)(0.f);
  for (int k0 = 0; k0 < 512; k0 += 64){
    __syncthreads();
    for (int i = 0; i < 4; i++){
      int c = t + i * 256;
      int row = c >> 3, ch = c & 7;
      *(bf16x8*)&Al[row][ch * 8] = *(const bf16x8*)&A[(size_t)(m0 + row) * 512 + k0 + ch * 8];
      *(bf16x8*)&Bl[row][ch * 8] = *(const bf16x8*)&B[(size_t)(n0 + row) * 512 + k0 + ch * 8];
    }
    __syncthreads();
    for (int dc = 0; dc < 2; dc++){
      bf16x8 af[4], bfr[4];
      for (int m = 0; m < 4; m++) af[m]  = *(const bf16x8*)&Al[wm + m * 16 + l15][dc * 32 + lg * 8];
      for (int n = 0; n < 4; n++) bfr[n] = *(const bf16x8*)&Bl[wn + n * 16 + l15][dc * 32 + lg * 8];
      for (int m = 0; m < 4; m++)
        for (int n = 0; n < 4; n++)
          acc[m][n] = mfma_bf16(af[m], bfr[n], acc[m][n]);
    }
  }
  for (int m = 0; m < 4; m++) for (int n = 0; n < 4; n++) for (int r = 0; r < 4; r++){
    int row = m0 + wm + m * 16 + lg * 4 + r;
    int col = n0 + wn + n * 16 + l15;
    float val = acc[m][n][r];
    if (MODE == 0){
      if (col < 512){
        int h = col >> 7, d = col & 127;
        qbuf[(((size_t)b * 4 + h) * 1024 + row) * 128 + d] = f2bf(val * 0.08838834764831845f);
      } else {
        int c2 = col - 512;
        int h = c2 >> 7, d = c2 & 127;
        kbuf[(((size_t)b * 4 + h) * 1024 + row) * 128 + d] = f2bf(val);
      }
    } else {
      vbuf[(((size_t)b * 4 + (row >> 7)) * 128 + (row & 127)) * 1024 + col] = f2bf(val);
    }
  }
}

// ---------------- K2: rel logits  Rel[bh][p][0:32]=rh(y), [32:64]=rw(j) ----------------
__global__ __launch_bounds__(64, 4) void k_rel(const unsigned short* __restrict__ qbuf,
                                               const float* __restrict__ relh,
                                               const float* __restrict__ relw,
                                               float* __restrict__ Rel){
  int xi = blockIdx.x;          // x (mode0) or i (mode1)
  int bh = blockIdx.y;
  int mode = blockIdx.z;
  int lane = threadIdx.x;
  int l15 = lane & 15, lg = lane >> 4;
  const float* rel = (mode == 0) ? relh : relw;
  f32x4 acc[2][2];
  for (int m = 0; m < 2; m++) for (int n = 0; n < 2; n++) acc[m][n] = (f32x4)(0.f);
  for (int dc = 0; dc < 4; dc++){
    bf16x8 af[2], bb[2];
    for (int m = 0; m < 2; m++){
      int p = (mode == 0) ? (xi * 32 + m * 16 + l15) : ((m * 16 + l15) * 32 + xi);
      af[m] = *(const bf16x8*)&qbuf[((size_t)bh * 1024 + p) * 128 + dc * 32 + lg * 8];
    }
    for (int n = 0; n < 2; n++){
      int mrow = n * 16 + l15 - xi + 31;      // in [0,62]
      const float* rp = &rel[(size_t)mrow * 128 + dc * 32 + lg * 8];
      f32x4 r0 = *(const f32x4*)rp;
      f32x4 r1 = *(const f32x4*)(rp + 4);
      bf16x8 t;
      for (int e = 0; e < 4; e++){ t[e] = (short)f2bf(r0[e]); t[e + 4] = (short)f2bf(r1[e]); }
      bb[n] = t;
    }
    for (int m = 0; m < 2; m++)
      for (int n = 0; n < 2; n++)
        acc[m][n] = mfma_bf16(af[m], bb[n], acc[m][n]);
  }
  for (int m = 0; m < 2; m++) for (int n = 0; n < 2; n++) for (int r = 0; r < 4; r++){
    int a = m * 16 + lg * 4 + r;
    int outc = n * 16 + l15;
    int p = (mode == 0) ? (xi * 32 + a) : (a * 32 + xi);
    Rel[((size_t)bh * 1024 + p) * 64 + ((mode == 0) ? outc : 32 + outc)] = acc[m][n][r];
  }
}

// ---------------- K3: fused flash attention ----------------
__global__ __launch_bounds__(256, 2) void k_attn(const unsigned short* __restrict__ qbuf,
                                                 const unsigned short* __restrict__ kbuf,
                                                 const unsigned short* __restrict__ vbuf,
                                                 const float* __restrict__ Rel,
                                                 float* __restrict__ out){
  __shared__ unsigned short Kl[64][136];   // K tile [key][d], rows 272B
  __shared__ unsigned short Vl[128][72];   // V^T tile [dv][key], rows 144B
  __shared__ unsigned short Pl[4][32][72]; // per-wave P [q][key], rows 144B
  int q0 = blockIdx.x * 128;
  int bh = blockIdx.y;
  int t = threadIdx.x;
  int lane = t & 63, w = t >> 6;
  int l15 = lane & 15, lg = lane >> 4;
  int qw = q0 + w * 32;
  const unsigned short* qg = qbuf + (size_t)bh * 1024 * 128;
  const unsigned short* kg = kbuf + (size_t)bh * 1024 * 128;
  const unsigned short* vg = vbuf + (size_t)bh * 128 * 1024;
  const float* relbh = Rel + (size_t)bh * 1024 * 64;

  bf16x8 qf[2][4];
  for (int cg = 0; cg < 2; cg++)
    for (int dc = 0; dc < 4; dc++)
      qf[cg][dc] = *(const bf16x8*)&qg[(size_t)(qw + cg * 16 + l15) * 128 + dc * 32 + lg * 8];

  float rw[2][2][4];
  for (int cg = 0; cg < 2; cg++)
    for (int kk = 0; kk < 2; kk++)
      for (int r = 0; r < 4; r++)
        rw[cg][kk][r] = relbh[(size_t)(qw + cg * 16 + l15) * 64 + 32 + kk * 16 + lg * 4 + r];

  f32x4 o[8][2];
  for (int rg = 0; rg < 8; rg++) for (int cg = 0; cg < 2; cg++) o[rg][cg] = (f32x4)(0.f);
  float mrun[2] = {-1e30f, -1e30f};
  float lrun[2] = {0.f, 0.f};

  for (int kv0 = 0; kv0 < 1024; kv0 += 64){
    __syncthreads();
    for (int i = 0; i < 4; i++){
      int c = t + i * 256;
      int row = c >> 4, ch = c & 15;
      *(bf16x8*)&Kl[row][ch * 8] = *(const bf16x8*)&kg[(size_t)(kv0 + row) * 128 + ch * 8];
    }
    for (int i = 0; i < 4; i++){
      int c = t + i * 256;
      int row = c >> 3, ch = c & 7;
      *(bf16x8*)&Vl[row][ch * 8] = *(const bf16x8*)&vg[(size_t)row * 1024 + kv0 + ch * 8];
    }
    __syncthreads();

    // S^T = K * Q^T : frags [g:key16][cg:q16]
    f32x4 s[4][2];
    for (int g = 0; g < 4; g++) for (int cg = 0; cg < 2; cg++) s[g][cg] = (f32x4)(0.f);
    for (int dc = 0; dc < 4; dc++){
      bf16x8 kf[4];
      for (int g = 0; g < 4; g++)
        kf[g] = *(const bf16x8*)&Kl[g * 16 + l15][dc * 32 + lg * 8];
      for (int g = 0; g < 4; g++)
        for (int cg = 0; cg < 2; cg++)
          s[g][cg] = mfma_bf16(kf[g], qf[cg][dc], s[g][cg]);
    }
    // rel add: element key = g*16 + lg*4 + r (local), q = cg*16 + l15
    int y0 = kv0 >> 5;
    float rh[2][2];
    for (int cg = 0; cg < 2; cg++){
      const float* rp = &relbh[(size_t)(qw + cg * 16 + l15) * 64];
      rh[cg][0] = rp[y0];
      rh[cg][1] = rp[y0 + 1];
    }
    for (int g = 0; g < 4; g++)
      for (int cg = 0; cg < 2; cg++)
        for (int r = 0; r < 4; r++)
          s[g][cg][r] += rh[cg][g >> 1] + rw[cg][g & 1][r];

    // online softmax (stats per q = cg*16 + l15, reduce over lane>>4 groups)
    float a[2];
    for (int cg = 0; cg < 2; cg++){
      float mt = s[0][cg][0];
      for (int g = 0; g < 4; g++) for (int r = 0; r < 4; r++) mt = fmaxf(mt, s[g][cg][r]);
      mt = fmaxf(mt, __shfl_xor(mt, 16, 64));
      mt = fmaxf(mt, __shfl_xor(mt, 32, 64));
      float mnew = fmaxf(mrun[cg], mt);
      a[cg] = __expf(mrun[cg] - mnew);
      mrun[cg] = mnew;
      float sum = 0.f;
      for (int g = 0; g < 4; g++) for (int r = 0; r < 4; r++){
        float e = __expf(s[g][cg][r] - mnew);
        s[g][cg][r] = e;
        sum += e;
      }
      sum += __shfl_xor(sum, 16, 64);
      sum += __shfl_xor(sum, 32, 64);
      lrun[cg] = lrun[cg] * a[cg] + sum;
    }
    // P -> bf16 -> LDS [q][key]
    for (int cg = 0; cg < 2; cg++)
      for (int g = 0; g < 4; g++){
        uint32_t p0 = (uint32_t)f2bf(s[g][cg][0]) | ((uint32_t)f2bf(s[g][cg][1]) << 16);
        uint32_t p1 = (uint32_t)f2bf(s[g][cg][2]) | ((uint32_t)f2bf(s[g][cg][3]) << 16);
        uint2 pv = make_uint2(p0, p1);
        *(uint2*)&Pl[w][cg * 16 + l15][g * 16 + lg * 4] = pv;
      }
    // rescale O
    for (int rg = 0; rg < 8; rg++)
      for (int cg = 0; cg < 2; cg++){
        o[rg][cg][0] *= a[cg]; o[rg][cg][1] *= a[cg];
        o[rg][cg][2] *= a[cg]; o[rg][cg][3] *= a[cg];
      }
    // O^T += V^T * P^T
    for (int kc = 0; kc < 2; kc++){
      bf16x8 pf[2];
      for (int cg = 0; cg < 2; cg++)
        pf[cg] = *(const bf16x8*)&Pl[w][cg * 16 + l15][kc * 32 + lg * 8];
      for (int rg = 0; rg < 8; rg++){
        bf16x8 vf = *(const bf16x8*)&Vl[rg * 16 + l15][kc * 32 + lg * 8];
        for (int cg = 0; cg < 2; cg++)
          o[rg][cg] = mfma_bf16(vf, pf[cg], o[rg][cg]);
      }
    }
  }
  float inv[2] = {1.f / lrun[0], 1.f / lrun[1]};
  float* outb = out + (size_t)bh * 128 * 1024;
  for (int rg = 0; rg < 8; rg++)
    for (int cg = 0; cg < 2; cg++)
      for (int r = 0; r < 4; r++){
        int dv = rg * 16 + lg * 4 + r;
        int p = qw + cg * 16 + l15;
        outb[(size_t)dv * 1024 + p] = o[rg][cg][r] * inv[cg];
      }
}

extern "C" void kernel_launch(void* const* d_in, const int* in_sizes, int n_in,
                              void* d_out, int out_size, void* d_ws, size_t ws_size,
                              hipStream_t stream){
  const float* fm   = (const float*)d_in[0];
  const float* wqk  = (const float*)d_in[1];
  const float* wv   = (const float*)d_in[2];
  const float* relh = (const float*)d_in[3];
  const float* relw = (const float*)d_in[4];
  float* out = (float*)d_out;
  char* ws = (char*)d_ws;
  if (ws_size < (size_t)68681728) return;  // need 64MB + 1.5MB

  unsigned short* qb = (unsigned short*)(ws);
  unsigned short* kb = (unsigned short*)(ws + ((size_t)16 << 20));
  unsigned short* vb = (unsigned short*)(ws + ((size_t)32 << 20));
  unsigned short* xt = (unsigned short*)(ws + ((size_t)48 << 20));
  float* Rel         = (float*)(ws + ((size_t)48 << 20));   // aliases xt (used after proj)
  unsigned short* wb = (unsigned short*)(ws + ((size_t)64 << 20));

  hipLaunchKernelGGL(k_transpose_cvt, dim3(32, 16, 16), dim3(256), 0, stream, fm, xt);
  hipLaunchKernelGGL(k_wcvt, dim3(768), dim3(256), 0, stream, wqk, wv, wb);
  hipLaunchKernelGGL(k_proj<0>, dim3(8, 8, 16), dim3(256), 0, stream, xt, wb, qb, kb, vb);
  hipLaunchKernelGGL(k_proj<1>, dim3(4, 8, 16), dim3(256), 0, stream,
                     wb + (size_t)1024 * 512, xt, qb, kb, vb);
  hipLaunchKernelGGL(k_rel, dim3(32, 64, 2), dim3(64), 0, stream, qb, relh, relw, Rel);
  hipLaunchKernelGGL(k_attn, dim3(8, 64), dim3(256), 0, stream, qb, kb, vb, Rel, out);
}

// Round 2
// 130.528 us; speedup vs baseline: 1.1761x; 1.1761x over previous
//
#include <hip/hip_runtime.h>
#include <stdint.h>

typedef __attribute__((ext_vector_type(4))) float f32x4;
typedef __attribute__((ext_vector_type(8))) short bf16x8;

#define DEV static __device__ __forceinline__

#define GLOAD16(g, l) __builtin_amdgcn_global_load_lds( \
    (const __attribute__((address_space(1))) void*)(g), \
    (__attribute__((address_space(3))) void*)(l), 16, 0, 0)

DEV unsigned short f2bf(float f){
  union { float f; uint32_t u; } v; v.f = f;
  return (unsigned short)((v.u + 0x7fffu + ((v.u >> 16) & 1u)) >> 16);
}

DEV f32x4 mfma_bf16(bf16x8 a, bf16x8 b, f32x4 c){
  return __builtin_amdgcn_mfma_f32_16x16x32_bf16(a, b, c, 0, 0, 0);
}

// ---------------- K0a: fm [b][c][l] f32 -> XT [b][l][c] bf16 ----------------
__global__ __launch_bounds__(256) void k_transpose_cvt(const float* __restrict__ fm,
                                                       unsigned short* __restrict__ xt){
  __shared__ float tile[32][33];
  int b = blockIdx.z, c0 = blockIdx.y * 32, l0 = blockIdx.x * 32;
  int tc = threadIdx.x & 31, tr = threadIdx.x >> 5;
  const float* src = fm + ((size_t)b * 512 + c0) * 1024 + l0;
  for (int i = 0; i < 4; i++){
    int r = tr + i * 8;
    tile[r][tc] = src[(size_t)r * 1024 + tc];
  }
  __syncthreads();
  unsigned short* dst = xt + ((size_t)b * 1024 + l0) * 512 + c0;
  for (int i = 0; i < 4; i++){
    int r = tr + i * 8;
    dst[(size_t)r * 512 + tc] = f2bf(tile[tc][r]);
  }
}

// ---------------- K0b: W concat(w_qk,w_v) f32 -> bf16 [1536][512] ----------------
__global__ __launch_bounds__(256) void k_wcvt(const float* __restrict__ wqk,
                                              const float* __restrict__ wv,
                                              unsigned short* __restrict__ wb){
  int idx = blockIdx.x * 256 + threadIdx.x;
  int e = idx * 4;
  if (e >= 1536 * 512) return;
  const float* src = (e < 1024 * 512) ? (wqk + e) : (wv + (e - 1024 * 512));
  f32x4 v = *(const f32x4*)src;
  unsigned short* d = wb + e;
  d[0] = f2bf(v[0]); d[1] = f2bf(v[1]); d[2] = f2bf(v[2]); d[3] = f2bf(v[3]);
}

// ---------------- K1: gemm_bt  C = A(MxK) * B(NxK)^T, bf16, K=512 ----------------
// m97-style: global_load_lds width-16 staging, linear LDS [128][64].
// MODE 0: A = XT_b [1024][512], B = Wqk [1024][512] -> C[l][o] -> q(scaled)/k [bh][l][d]
// MODE 1: A = Wv [512][512],   B = XT_b [1024][512] -> C[o][l] -> v [bh][dv][l]
template<int MODE>
__global__ __launch_bounds__(256, 3) void k_proj(const unsigned short* __restrict__ Abase,
                                                 const unsigned short* __restrict__ Bbase,
                                                 unsigned short* __restrict__ qbuf,
                                                 unsigned short* __restrict__ kbuf,
                                                 unsigned short* __restrict__ vbuf){
  __shared__ unsigned short Al[128][64];
  __shared__ unsigned short Bl[128][64];
  int b = blockIdx.z;
  const unsigned short* A = Abase + (MODE == 0 ? (size_t)b * 1024 * 512 : 0);
  const unsigned short* B = Bbase + (MODE == 0 ? 0 : (size_t)b * 1024 * 512);
  int m0 = blockIdx.x * 128, n0 = blockIdx.y * 128;
  int t = threadIdx.x;
  int lane = t & 63, w = t >> 6;
  int wm = (w >> 1) * 64, wn = (w & 1) * 64;
  int l15 = lane & 15, lg = lane >> 4;
  int srow = lane >> 3;          // 0..7 within chunk
  int scol = (lane & 7) * 8;     // element col within BK
  f32x4 acc[4][4];
  for (int m = 0; m < 4; m++) for (int n = 0; n < 4; n++) acc[m][n] = (f32x4)(0.f);
  for (int k0 = 0; k0 < 512; k0 += 64){
    __syncthreads();
    #pragma unroll
    for (int i = 0; i < 4; i++){
      int j = w * 4 + i;                 // chunk 0..15, 8 rows each
      GLOAD16(&A[(size_t)(m0 + j * 8 + srow) * 512 + k0 + scol], &Al[j * 8][0]);
      GLOAD16(&B[(size_t)(n0 + j * 8 + srow) * 512 + k0 + scol], &Bl[j * 8][0]);
    }
    __syncthreads();
    for (int dc = 0; dc < 2; dc++){
      bf16x8 af[4], bfr[4];
      for (int m = 0; m < 4; m++) af[m]  = *(const bf16x8*)&Al[wm + m * 16 + l15][dc * 32 + lg * 8];
      for (int n = 0; n < 4; n++) bfr[n] = *(const bf16x8*)&Bl[wn + n * 16 + l15][dc * 32 + lg * 8];
      for (int m = 0; m < 4; m++)
        for (int n = 0; n < 4; n++)
          acc[m][n] = mfma_bf16(af[m], bfr[n], acc[m][n]);
    }
  }
  for (int m = 0; m < 4; m++) for (int n = 0; n < 4; n++) for (int r = 0; r < 4; r++){
    int row = m0 + wm + m * 16 + lg * 4 + r;
    int col = n0 + wn + n * 16 + l15;
    float val = acc[m][n][r];
    if (MODE == 0){
      if (col < 512){
        int h = col >> 7, d = col & 127;
        qbuf[(((size_t)b * 4 + h) * 1024 + row) * 128 + d] = f2bf(val * 0.08838834764831845f);
      } else {
        int c2 = col - 512;
        int h = c2 >> 7, d = c2 & 127;
        kbuf[(((size_t)b * 4 + h) * 1024 + row) * 128 + d] = f2bf(val);
      }
    } else {
      vbuf[(((size_t)b * 4 + (row >> 7)) * 128 + (row & 127)) * 1024 + col] = f2bf(val);
    }
  }
}

// ---------------- K2: rel logits  Rel[bh][p][0:32]=rh(y), [32:64]=rw(j) ----------------
__global__ __launch_bounds__(64, 4) void k_rel(const unsigned short* __restrict__ qbuf,
                                               const float* __restrict__ relh,
                                               const float* __restrict__ relw,
                                               float* __restrict__ Rel){
  int xi = blockIdx.x;          // x (mode0) or i (mode1)
  int bh = blockIdx.y;
  int mode = blockIdx.z;
  int lane = threadIdx.x;
  int l15 = lane & 15, lg = lane >> 4;
  const float* rel = (mode == 0) ? relh : relw;
  f32x4 acc[2][2];
  for (int m = 0; m < 2; m++) for (int n = 0; n < 2; n++) acc[m][n] = (f32x4)(0.f);
  for (int dc = 0; dc < 4; dc++){
    bf16x8 af[2], bb[2];
    for (int m = 0; m < 2; m++){
      int p = (mode == 0) ? (xi * 32 + m * 16 + l15) : ((m * 16 + l15) * 32 + xi);
      af[m] = *(const bf16x8*)&qbuf[((size_t)bh * 1024 + p) * 128 + dc * 32 + lg * 8];
    }
    for (int n = 0; n < 2; n++){
      int mrow = n * 16 + l15 - xi + 31;      // in [0,62]
      const float* rp = &rel[(size_t)mrow * 128 + dc * 32 + lg * 8];
      f32x4 r0 = *(const f32x4*)rp;
      f32x4 r1 = *(const f32x4*)(rp + 4);
      bf16x8 tt;
      for (int e = 0; e < 4; e++){ tt[e] = (short)f2bf(r0[e]); tt[e + 4] = (short)f2bf(r1[e]); }
      bb[n] = tt;
    }
    for (int m = 0; m < 2; m++)
      for (int n = 0; n < 2; n++)
        acc[m][n] = mfma_bf16(af[m], bb[n], acc[m][n]);
  }
  for (int m = 0; m < 2; m++) for (int n = 0; n < 2; n++) for (int r = 0; r < 4; r++){
    int a = m * 16 + lg * 4 + r;
    int outc = n * 16 + l15;
    int p = (mode == 0) ? (xi * 32 + a) : (a * 32 + xi);
    Rel[((size_t)bh * 1024 + p) * 64 + ((mode == 0) ? outc : 32 + outc)] = acc[m][n][r];
  }
}

// ---------------- K3: fused flash attention (T14 reg-prefetch + defer-max) ----------------
__global__ __launch_bounds__(256, 2) void k_attn(const unsigned short* __restrict__ qbuf,
                                                 const unsigned short* __restrict__ kbuf,
                                                 const unsigned short* __restrict__ vbuf,
                                                 const float* __restrict__ Rel,
                                                 float* __restrict__ out){
  __shared__ unsigned short Kl[64][136];   // K tile [key][d], rows 272B (near-min conflicts)
  __shared__ unsigned short Vl[128][72];   // V^T tile [dv][key], rows 144B
  __shared__ unsigned short Pl[4][32][72]; // per-wave P [q][key], rows 144B
  int bh = blockIdx.x;                      // bh fast axis -> same-bh blocks share an XCD L2
  int q0 = blockIdx.y * 128;
  int t = threadIdx.x;
  int lane = t & 63, w = t >> 6;
  int l15 = lane & 15, lg = lane >> 4;
  int qw = q0 + w * 32;
  const unsigned short* qg = qbuf + (size_t)bh * 1024 * 128;
  const unsigned short* kg = kbuf + (size_t)bh * 1024 * 128;
  const unsigned short* vg = vbuf + (size_t)bh * 128 * 1024;
  const float* relbh = Rel + (size_t)bh * 1024 * 64;

  bf16x8 qf[2][4];
  for (int cg = 0; cg < 2; cg++)
    for (int dc = 0; dc < 4; dc++)
      qf[cg][dc] = *(const bf16x8*)&qg[(size_t)(qw + cg * 16 + l15) * 128 + dc * 32 + lg * 8];

  float rw[2][2][4];
  for (int cg = 0; cg < 2; cg++)
    for (int kk = 0; kk < 2; kk++)
      for (int r = 0; r < 4; r++)
        rw[cg][kk][r] = relbh[(size_t)(qw + cg * 16 + l15) * 64 + 32 + kk * 16 + lg * 4 + r];

  // staging address components
  int krow = (t + 0) >> 4;        // base pattern; per-i offsets below
  (void)krow;
  f32x4 o[8][2];
  for (int rg = 0; rg < 8; rg++) for (int cg = 0; cg < 2; cg++) o[rg][cg] = (f32x4)(0.f);
  float mrun[2] = {-1e30f, -1e30f};
  float lrun[2] = {0.f, 0.f};

  bf16x8 kpre[4], vpre[4];
  #pragma unroll
  for (int i = 0; i < 4; i++){
    int c = t + i * 256;
    kpre[i] = *(const bf16x8*)&kg[(size_t)(c >> 4) * 128 + (c & 15) * 8];
    vpre[i] = *(const bf16x8*)&vg[(size_t)(c >> 3) * 1024 + 0 + (c & 7) * 8];
  }

  for (int kv0 = 0; kv0 < 1024; kv0 += 64){
    __syncthreads();
    #pragma unroll
    for (int i = 0; i < 4; i++){
      int c = t + i * 256;
      *(bf16x8*)&Kl[c >> 4][(c & 15) * 8] = kpre[i];
      *(bf16x8*)&Vl[c >> 3][(c & 7) * 8] = vpre[i];
    }
    __syncthreads();
    if (kv0 + 64 < 1024){
      int kvn = kv0 + 64;
      #pragma unroll
      for (int i = 0; i < 4; i++){
        int c = t + i * 256;
        kpre[i] = *(const bf16x8*)&kg[(size_t)(kvn + (c >> 4)) * 128 + (c & 15) * 8];
        vpre[i] = *(const bf16x8*)&vg[(size_t)(c >> 3) * 1024 + kvn + (c & 7) * 8];
      }
    }

    // S^T = K * Q^T : frags [g:key16][cg:q16]
    f32x4 s[4][2];
    for (int g = 0; g < 4; g++) for (int cg = 0; cg < 2; cg++) s[g][cg] = (f32x4)(0.f);
    for (int dc = 0; dc < 4; dc++){
      bf16x8 kf[4];
      for (int g = 0; g < 4; g++)
        kf[g] = *(const bf16x8*)&Kl[g * 16 + l15][dc * 32 + lg * 8];
      for (int g = 0; g < 4; g++)
        for (int cg = 0; cg < 2; cg++)
          s[g][cg] = mfma_bf16(kf[g], qf[cg][dc], s[g][cg]);
    }
    // rel add: element key = g*16 + lg*4 + r (local), q = cg*16 + l15
    int y0 = kv0 >> 5;
    float rh[2][2];
    for (int cg = 0; cg < 2; cg++){
      const float* rp = &relbh[(size_t)(qw + cg * 16 + l15) * 64];
      rh[cg][0] = rp[y0];
      rh[cg][1] = rp[y0 + 1];
    }
    for (int g = 0; g < 4; g++)
      for (int cg = 0; cg < 2; cg++)
        for (int r = 0; r < 4; r++)
          s[g][cg][r] += rh[cg][g >> 1] + rw[cg][g & 1][r];

    // online softmax with defer-max (T13): stats per q = cg*16+l15
    float mt[2];
    for (int cg = 0; cg < 2; cg++){
      float m_ = s[0][cg][0];
      for (int g = 0; g < 4; g++) for (int r = 0; r < 4; r++) m_ = fmaxf(m_, s[g][cg][r]);
      m_ = fmaxf(m_, __shfl_xor(m_, 16, 64));
      m_ = fmaxf(m_, __shfl_xor(m_, 32, 64));
      mt[cg] = m_;
    }
    bool defer = (mt[0] <= mrun[0] + 8.f) && (mt[1] <= mrun[1] + 8.f);
    if (!__all((int)defer)){
      for (int cg = 0; cg < 2; cg++){
        float mnew = fmaxf(mrun[cg], mt[cg]);
        float a_ = __expf(mrun[cg] - mnew);
        mrun[cg] = mnew;
        lrun[cg] *= a_;
        for (int rg = 0; rg < 8; rg++){
          o[rg][cg][0] *= a_; o[rg][cg][1] *= a_;
          o[rg][cg][2] *= a_; o[rg][cg][3] *= a_;
        }
      }
    }
    for (int cg = 0; cg < 2; cg++){
      float sum = 0.f;
      for (int g = 0; g < 4; g++) for (int r = 0; r < 4; r++){
        float e = __expf(s[g][cg][r] - mrun[cg]);
        s[g][cg][r] = e;
        sum += e;
      }
      sum += __shfl_xor(sum, 16, 64);
      sum += __shfl_xor(sum, 32, 64);
      lrun[cg] += sum;
    }
    // P -> bf16 -> LDS [q][key]
    for (int cg = 0; cg < 2; cg++)
      for (int g = 0; g < 4; g++){
        uint32_t p0 = (uint32_t)f2bf(s[g][cg][0]) | ((uint32_t)f2bf(s[g][cg][1]) << 16);
        uint32_t p1 = (uint32_t)f2bf(s[g][cg][2]) | ((uint32_t)f2bf(s[g][cg][3]) << 16);
        uint2 pv = make_uint2(p0, p1);
        *(uint2*)&Pl[w][cg * 16 + l15][g * 16 + lg * 4] = pv;
      }
    // O^T += V^T * P^T
    for (int kc = 0; kc < 2; kc++){
      bf16x8 pf[2];
      for (int cg = 0; cg < 2; cg++)
        pf[cg] = *(const bf16x8*)&Pl[w][cg * 16 + l15][kc * 32 + lg * 8];
      for (int rg = 0; rg < 8; rg++){
        bf16x8 vf = *(const bf16x8*)&Vl[rg * 16 + l15][kc * 32 + lg * 8];
        for (int cg = 0; cg < 2; cg++)
          o[rg][cg] = mfma_bf16(vf, pf[cg], o[rg][cg]);
      }
    }
  }
  float inv[2] = {1.f / lrun[0], 1.f / lrun[1]};
  float* outb = out + (size_t)bh * 128 * 1024;
  for (int rg = 0; rg < 8; rg++)
    for (int cg = 0; cg < 2; cg++)
      for (int r = 0; r < 4; r++){
        int dv = rg * 16 + lg * 4 + r;
        int p = qw + cg * 16 + l15;
        outb[(size_t)dv * 1024 + p] = o[rg][cg][r] * inv[cg];
      }
}

extern "C" void kernel_launch(void* const* d_in, const int* in_sizes, int n_in,
                              void* d_out, int out_size, void* d_ws, size_t ws_size,
                              hipStream_t stream){
  const float* fm   = (const float*)d_in[0];
  const float* wqk  = (const float*)d_in[1];
  const float* wv   = (const float*)d_in[2];
  const float* relh = (const float*)d_in[3];
  const float* relw = (const float*)d_in[4];
  float* out = (float*)d_out;
  char* ws = (char*)d_ws;
  if (ws_size < (size_t)68681728) return;  // need 64MB + 1.5MB

  unsigned short* qb = (unsigned short*)(ws);
  unsigned short* kb = (unsigned short*)(ws + ((size_t)16 << 20));
  unsigned short* vb = (unsigned short*)(ws + ((size_t)32 << 20));
  unsigned short* xt = (unsigned short*)(ws + ((size_t)48 << 20));
  float* Rel         = (float*)(ws + ((size_t)48 << 20));   // aliases xt (used after proj)
  unsigned short* wb = (unsigned short*)(ws + ((size_t)64 << 20));

  hipLaunchKernelGGL(k_transpose_cvt, dim3(32, 16, 16), dim3(256), 0, stream, fm, xt);
  hipLaunchKernelGGL(k_wcvt, dim3(768), dim3(256), 0, stream, wqk, wv, wb);
  hipLaunchKernelGGL(k_proj<0>, dim3(8, 8, 16), dim3(256), 0, stream, xt, wb, qb, kb, vb);
  hipLaunchKernelGGL(k_proj<1>, dim3(4, 8, 16), dim3(256), 0, stream,
                     wb + (size_t)1024 * 512, xt, qb, kb, vb);
  hipLaunchKernelGGL(k_rel, dim3(32, 64, 2), dim3(64), 0, stream, qb, relh, relw, Rel);
  hipLaunchKernelGGL(k_attn, dim3(64, 8), dim3(256), 0, stream, qb, kb, vb, Rel, out);
}

// Round 3
// 123.383 us; speedup vs baseline: 1.2442x; 1.0579x over previous
//
#include <hip/hip_runtime.h>
#include <stdint.h>

typedef __attribute__((ext_vector_type(4))) float f32x4;
typedef __attribute__((ext_vector_type(8))) short bf16x8;

#define DEV static __device__ __forceinline__

#define GLOAD16(g, l) __builtin_amdgcn_global_load_lds( \
    (const __attribute__((address_space(1))) void*)(g), \
    (__attribute__((address_space(3))) void*)(l), 16, 0, 0)

DEV unsigned short f2bf(float f){
  union { float f; uint32_t u; } v; v.f = f;
  return (unsigned short)((v.u + 0x7fffu + ((v.u >> 16) & 1u)) >> 16);
}

DEV uint32_t cvtpk(float a, float b){
  uint32_t r; asm("v_cvt_pk_bf16_f32 %0, %1, %2" : "=v"(r) : "v"(a), "v"(b)); return r;
}

DEV f32x4 mfma_bf16(bf16x8 a, bf16x8 b, f32x4 c){
  return __builtin_amdgcn_mfma_f32_16x16x32_bf16(a, b, c, 0, 0, 0);
}

// ---------------- K0a: fm [b][c][l] f32 -> XT [b][l][c] bf16 (64x64 tiles) ----------------
__global__ __launch_bounds__(256) void k_transpose_cvt(const float* __restrict__ fm,
                                                       unsigned short* __restrict__ xt){
  __shared__ float tile[64][65];
  int b = blockIdx.z, c0 = blockIdx.y * 64, l0 = blockIdx.x * 64;
  int t = threadIdx.x;
  int lr = t >> 4;
  int lc4 = (t & 15) * 4;
  const float* src = fm + ((size_t)b * 512 + c0) * 1024 + l0;
  #pragma unroll
  for (int i = 0; i < 4; i++){
    int r = lr + i * 16;
    f32x4 v = *(const f32x4*)&src[(size_t)r * 1024 + lc4];
    tile[r][lc4] = v[0]; tile[r][lc4 + 1] = v[1];
    tile[r][lc4 + 2] = v[2]; tile[r][lc4 + 3] = v[3];
  }
  __syncthreads();
  int j = t & 7;
  int lrow = t >> 3;
  unsigned short* dst = xt + ((size_t)b * 1024 + l0) * 512 + c0;
  #pragma unroll
  for (int i = 0; i < 2; i++){
    int l = lrow + i * 32;
    unsigned short tmp[8];
    #pragma unroll
    for (int u = 0; u < 8; u++) tmp[u] = f2bf(tile[j * 8 + u][l]);
    *(uint4*)&dst[(size_t)l * 512 + j * 8] = *(const uint4*)tmp;
  }
}

// ---------------- K0b: W concat(w_qk,w_v) f32 -> bf16 [1536][512] ----------------
__global__ __launch_bounds__(256) void k_wcvt(const float* __restrict__ wqk,
                                              const float* __restrict__ wv,
                                              unsigned short* __restrict__ wb){
  int idx = blockIdx.x * 256 + threadIdx.x;
  int e = idx * 4;
  if (e >= 1536 * 512) return;
  const float* src = (e < 1024 * 512) ? (wqk + e) : (wv + (e - 1024 * 512));
  f32x4 v = *(const f32x4*)src;
  unsigned short* d = wb + e;
  d[0] = f2bf(v[0]); d[1] = f2bf(v[1]); d[2] = f2bf(v[2]); d[3] = f2bf(v[3]);
}

// ---------------- K1: gemm_bt  C = A(MxK) * B(NxK)^T, bf16, K=512 ----------------
template<int MODE>
__global__ __launch_bounds__(256, 3) void k_proj(const unsigned short* __restrict__ Abase,
                                                 const unsigned short* __restrict__ Bbase,
                                                 unsigned short* __restrict__ qbuf,
                                                 unsigned short* __restrict__ kbuf,
                                                 unsigned short* __restrict__ vbuf){
  __shared__ unsigned short Al[128][64];
  __shared__ unsigned short Bl[128][64];
  int b = blockIdx.z;
  const unsigned short* A = Abase + (MODE == 0 ? (size_t)b * 1024 * 512 : 0);
  const unsigned short* B = Bbase + (MODE == 0 ? 0 : (size_t)b * 1024 * 512);
  int m0 = blockIdx.x * 128, n0 = blockIdx.y * 128;
  int t = threadIdx.x;
  int lane = t & 63, w = t >> 6;
  int wm = (w >> 1) * 64, wn = (w & 1) * 64;
  int l15 = lane & 15, lg = lane >> 4;
  int srow = lane >> 3;
  int scol = (lane & 7) * 8;
  f32x4 acc[4][4];
  for (int m = 0; m < 4; m++) for (int n = 0; n < 4; n++) acc[m][n] = (f32x4)(0.f);
  for (int k0 = 0; k0 < 512; k0 += 64){
    __syncthreads();
    #pragma unroll
    for (int i = 0; i < 4; i++){
      int j = w * 4 + i;
      GLOAD16(&A[(size_t)(m0 + j * 8 + srow) * 512 + k0 + scol], &Al[j * 8][0]);
      GLOAD16(&B[(size_t)(n0 + j * 8 + srow) * 512 + k0 + scol], &Bl[j * 8][0]);
    }
    __syncthreads();
    for (int dc = 0; dc < 2; dc++){
      bf16x8 af[4], bfr[4];
      for (int m = 0; m < 4; m++) af[m]  = *(const bf16x8*)&Al[wm + m * 16 + l15][dc * 32 + lg * 8];
      for (int n = 0; n < 4; n++) bfr[n] = *(const bf16x8*)&Bl[wn + n * 16 + l15][dc * 32 + lg * 8];
      for (int m = 0; m < 4; m++)
        for (int n = 0; n < 4; n++)
          acc[m][n] = mfma_bf16(af[m], bfr[n], acc[m][n]);
    }
  }
  for (int m = 0; m < 4; m++) for (int n = 0; n < 4; n++) for (int r = 0; r < 4; r++){
    int row = m0 + wm + m * 16 + lg * 4 + r;
    int col = n0 + wn + n * 16 + l15;
    float val = acc[m][n][r];
    if (MODE == 0){
      if (col < 512){
        int h = col >> 7, d = col & 127;
        qbuf[(((size_t)b * 4 + h) * 1024 + row) * 128 + d] = f2bf(val * 0.08838834764831845f);
      } else {
        int c2 = col - 512;
        int h = c2 >> 7, d = c2 & 127;
        kbuf[(((size_t)b * 4 + h) * 1024 + row) * 128 + d] = f2bf(val);
      }
    } else {
      vbuf[(((size_t)b * 4 + (row >> 7)) * 128 + (row & 127)) * 1024 + col] = f2bf(val);
    }
  }
}

// ---------------- K2: rel logits  Rel[bh][p][0:32]=rh(y), [32:64]=rw(j) ----------------
__global__ __launch_bounds__(64, 4) void k_rel(const unsigned short* __restrict__ qbuf,
                                               const float* __restrict__ relh,
                                               const float* __restrict__ relw,
                                               float* __restrict__ Rel){
  int xi = blockIdx.x;
  int bh = blockIdx.y;
  int mode = blockIdx.z;
  int lane = threadIdx.x;
  int l15 = lane & 15, lg = lane >> 4;
  const float* rel = (mode == 0) ? relh : relw;
  f32x4 acc[2][2];
  for (int m = 0; m < 2; m++) for (int n = 0; n < 2; n++) acc[m][n] = (f32x4)(0.f);
  for (int dc = 0; dc < 4; dc++){
    bf16x8 af[2], bb[2];
    for (int m = 0; m < 2; m++){
      int p = (mode == 0) ? (xi * 32 + m * 16 + l15) : ((m * 16 + l15) * 32 + xi);
      af[m] = *(const bf16x8*)&qbuf[((size_t)bh * 1024 + p) * 128 + dc * 32 + lg * 8];
    }
    for (int n = 0; n < 2; n++){
      int mrow = n * 16 + l15 - xi + 31;
      const float* rp = &rel[(size_t)mrow * 128 + dc * 32 + lg * 8];
      f32x4 r0 = *(const f32x4*)rp;
      f32x4 r1 = *(const f32x4*)(rp + 4);
      bf16x8 tt;
      for (int e = 0; e < 4; e++){ tt[e] = (short)f2bf(r0[e]); tt[e + 4] = (short)f2bf(r1[e]); }
      bb[n] = tt;
    }
    for (int m = 0; m < 2; m++)
      for (int n = 0; n < 2; n++)
        acc[m][n] = mfma_bf16(af[m], bb[n], acc[m][n]);
  }
  for (int m = 0; m < 2; m++) for (int n = 0; n < 2; n++) for (int r = 0; r < 4; r++){
    int a = m * 16 + lg * 4 + r;
    int outc = n * 16 + l15;
    int p = (mode == 0) ? (xi * 32 + a) : (a * 32 + xi);
    Rel[((size_t)bh * 1024 + p) * 64 + ((mode == 0) ? outc : 32 + outc)] = acc[m][n][r];
  }
}

// ---------------- K3: fused flash attention (T2 swizzle + T14 + T13 + T5) ----------------
__global__ __launch_bounds__(256, 2) void k_attn(const unsigned short* __restrict__ qbuf,
                                                 const unsigned short* __restrict__ kbuf,
                                                 const unsigned short* __restrict__ vbuf,
                                                 const float* __restrict__ Rel,
                                                 float* __restrict__ out){
  // XOR-swizzled linear tiles: elem ^= (row&7)*8 within each row
  __shared__ unsigned short Kl[64 * 128];   // [key][d]
  __shared__ unsigned short Vl[128 * 64];   // [dv][key]
  __shared__ unsigned short Pl[4][32 * 64]; // per-wave [q][key]
  int bh = blockIdx.x;
  int q0 = blockIdx.y * 128;
  int t = threadIdx.x;
  int lane = t & 63, w = t >> 6;
  int l15 = lane & 15, lg = lane >> 4;
  int swz = (l15 & 7) * 8;
  int qw = q0 + w * 32;
  const unsigned short* qg = qbuf + (size_t)bh * 1024 * 128;
  const unsigned short* kg = kbuf + (size_t)bh * 1024 * 128;
  const unsigned short* vg = vbuf + (size_t)bh * 128 * 1024;
  const float* relbh = Rel + (size_t)bh * 1024 * 64;

  bf16x8 qf[2][4];
  for (int cg = 0; cg < 2; cg++)
    for (int dc = 0; dc < 4; dc++)
      qf[cg][dc] = *(const bf16x8*)&qg[(size_t)(qw + cg * 16 + l15) * 128 + dc * 32 + lg * 8];

  float rw[2][2][4];
  for (int cg = 0; cg < 2; cg++)
    for (int kk = 0; kk < 2; kk++)
      for (int r = 0; r < 4; r++)
        rw[cg][kk][r] = relbh[(size_t)(qw + cg * 16 + l15) * 64 + 32 + kk * 16 + lg * 4 + r];

  f32x4 o[8][2];
  for (int rg = 0; rg < 8; rg++) for (int cg = 0; cg < 2; cg++) o[rg][cg] = (f32x4)(0.f);
  float mrun[2] = {-1e30f, -1e30f};
  float lrun[2] = {0.f, 0.f};

  bf16x8 kpre[4], vpre[4];
  #pragma unroll
  for (int i = 0; i < 4; i++){
    int c = t + i * 256;
    kpre[i] = *(const bf16x8*)&kg[(size_t)(c >> 4) * 128 + (c & 15) * 8];
    vpre[i] = *(const bf16x8*)&vg[(size_t)(c >> 3) * 1024 + (c & 7) * 8];
  }

  for (int kv0 = 0; kv0 < 1024; kv0 += 64){
    __syncthreads();
    #pragma unroll
    for (int i = 0; i < 4; i++){
      int c = t + i * 256;
      int kr = c >> 4;
      int vr = c >> 3;
      *(bf16x8*)&Kl[kr * 128 + (((c & 15) * 8) ^ ((kr & 7) * 8))] = kpre[i];
      *(bf16x8*)&Vl[vr * 64 + (((c & 7) * 8) ^ ((vr & 7) * 8))] = vpre[i];
    }
    __syncthreads();
    if (kv0 + 64 < 1024){
      int kvn = kv0 + 64;
      #pragma unroll
      for (int i = 0; i < 4; i++){
        int c = t + i * 256;
        kpre[i] = *(const bf16x8*)&kg[(size_t)(kvn + (c >> 4)) * 128 + (c & 15) * 8];
        vpre[i] = *(const bf16x8*)&vg[(size_t)(c >> 3) * 1024 + kvn + (c & 7) * 8];
      }
    }

    // S^T = K * Q^T
    f32x4 s[4][2];
    for (int g = 0; g < 4; g++) for (int cg = 0; cg < 2; cg++) s[g][cg] = (f32x4)(0.f);
    __builtin_amdgcn_s_setprio(1);
    for (int dc = 0; dc < 4; dc++){
      bf16x8 kf[4];
      for (int g = 0; g < 4; g++)
        kf[g] = *(const bf16x8*)&Kl[(g * 16 + l15) * 128 + ((dc * 32 + lg * 8) ^ swz)];
      for (int g = 0; g < 4; g++)
        for (int cg = 0; cg < 2; cg++)
          s[g][cg] = mfma_bf16(kf[g], qf[cg][dc], s[g][cg]);
    }
    __builtin_amdgcn_s_setprio(0);

    int y0 = kv0 >> 5;
    float rh[2][2];
    for (int cg = 0; cg < 2; cg++){
      const float* rp = &relbh[(size_t)(qw + cg * 16 + l15) * 64];
      rh[cg][0] = rp[y0];
      rh[cg][1] = rp[y0 + 1];
    }
    for (int g = 0; g < 4; g++)
      for (int cg = 0; cg < 2; cg++)
        for (int r = 0; r < 4; r++)
          s[g][cg][r] += rh[cg][g >> 1] + rw[cg][g & 1][r];

    // online softmax with defer-max
    float mt[2];
    for (int cg = 0; cg < 2; cg++){
      float m_ = s[0][cg][0];
      for (int g = 0; g < 4; g++) for (int r = 0; r < 4; r++) m_ = fmaxf(m_, s[g][cg][r]);
      m_ = fmaxf(m_, __shfl_xor(m_, 16, 64));
      m_ = fmaxf(m_, __shfl_xor(m_, 32, 64));
      mt[cg] = m_;
    }
    bool defer = (mt[0] <= mrun[0] + 8.f) && (mt[1] <= mrun[1] + 8.f);
    if (!__all((int)defer)){
      for (int cg = 0; cg < 2; cg++){
        float mnew = fmaxf(mrun[cg], mt[cg]);
        float a_ = __expf(mrun[cg] - mnew);
        mrun[cg] = mnew;
        lrun[cg] *= a_;
        for (int rg = 0; rg < 8; rg++) o[rg][cg] *= a_;
      }
    }
    for (int cg = 0; cg < 2; cg++){
      float sum = 0.f;
      for (int g = 0; g < 4; g++) for (int r = 0; r < 4; r++){
        float e = __expf(s[g][cg][r] - mrun[cg]);
        s[g][cg][r] = e;
        sum += e;
      }
      sum += __shfl_xor(sum, 16, 64);
      sum += __shfl_xor(sum, 32, 64);
      lrun[cg] += sum;
    }
    // P -> bf16 -> swizzled per-wave LDS [q][key]
    for (int cg = 0; cg < 2; cg++)
      for (int g = 0; g < 4; g++){
        uint2 pv = make_uint2(cvtpk(s[g][cg][0], s[g][cg][1]),
                              cvtpk(s[g][cg][2], s[g][cg][3]));
        *(uint2*)&Pl[w][(cg * 16 + l15) * 64 + ((g * 16 + lg * 4) ^ swz)] = pv;
      }
    // O^T += V^T * P^T
    __builtin_amdgcn_s_setprio(1);
    for (int kc = 0; kc < 2; kc++){
      bf16x8 pf[2];
      for (int cg = 0; cg < 2; cg++)
        pf[cg] = *(const bf16x8*)&Pl[w][(cg * 16 + l15) * 64 + ((kc * 32 + lg * 8) ^ swz)];
      for (int rg = 0; rg < 8; rg++){
        bf16x8 vf = *(const bf16x8*)&Vl[(rg * 16 + l15) * 64 + ((kc * 32 + lg * 8) ^ swz)];
        for (int cg = 0; cg < 2; cg++)
          o[rg][cg] = mfma_bf16(vf, pf[cg], o[rg][cg]);
      }
    }
    __builtin_amdgcn_s_setprio(0);
  }
  float inv[2] = {1.f / lrun[0], 1.f / lrun[1]};
  float* outb = out + (size_t)bh * 128 * 1024;
  for (int rg = 0; rg < 8; rg++)
    for (int cg = 0; cg < 2; cg++)
      for (int r = 0; r < 4; r++){
        int dv = rg * 16 + lg * 4 + r;
        int p = qw + cg * 16 + l15;
        outb[(size_t)dv * 1024 + p] = o[rg][cg][r] * inv[cg];
      }
}

extern "C" void kernel_launch(void* const* d_in, const int* in_sizes, int n_in,
                              void* d_out, int out_size, void* d_ws, size_t ws_size,
                              hipStream_t stream){
  const float* fm   = (const float*)d_in[0];
  const float* wqk  = (const float*)d_in[1];
  const float* wv   = (const float*)d_in[2];
  const float* relh = (const float*)d_in[3];
  const float* relw = (const float*)d_in[4];
  float* out = (float*)d_out;
  char* ws = (char*)d_ws;
  if (ws_size < (size_t)68681728) return;

  unsigned short* qb = (unsigned short*)(ws);
  unsigned short* kb = (unsigned short*)(ws + ((size_t)16 << 20));
  unsigned short* vb = (unsigned short*)(ws + ((size_t)32 << 20));
  unsigned short* xt = (unsigned short*)(ws + ((size_t)48 << 20));
  float* Rel         = (float*)(ws + ((size_t)48 << 20));
  unsigned short* wb = (unsigned short*)(ws + ((size_t)64 << 20));

  hipLaunchKernelGGL(k_transpose_cvt, dim3(16, 8, 16), dim3(256), 0, stream, fm, xt);
  hipLaunchKernelGGL(k_wcvt, dim3(768), dim3(256), 0, stream, wqk, wv, wb);
  hipLaunchKernelGGL(k_proj<0>, dim3(8, 8, 16), dim3(256), 0, stream, xt, wb, qb, kb, vb);
  hipLaunchKernelGGL(k_proj<1>, dim3(4, 8, 16), dim3(256), 0, stream,
                     wb + (size_t)1024 * 512, xt, qb, kb, vb);
  hipLaunchKernelGGL(k_rel, dim3(32, 64, 2), dim3(64), 0, stream, qb, relh, relw, Rel);
  hipLaunchKernelGGL(k_attn, dim3(64, 8), dim3(256), 0, stream, qb, kb, vb, Rel, out);
}